// Round 1
// baseline (69823.383 us; speedup 1.0000x reference)
//
#include <hip/hip_runtime.h>

#define SEQL 131072
#define HID 48
#define NG 192     // 4*HID
#define PRED 64

__device__ __forceinline__ float sigm(float v) {
    return 1.0f / (1.0f + __expf(-v));
}
__device__ __forceinline__ float tanh_fast(float v) {
    // exact identity tanh(v) = 1 - 2/(e^{2v}+1); safe at +/-inf
    return 1.0f - 2.0f / (__expf(2.0f * v) + 1.0f);
}

__global__ __launch_bounds__(NG, 1) void lstm_all(
    const float* __restrict__ x,      // 2*SEQL
    const float* __restrict__ W_ih,   // 192*2
    const float* __restrict__ W_hh,   // 192*48 row-major
    const float* __restrict__ b_ih,   // 192
    const float* __restrict__ b_hh,   // 192
    const float* __restrict__ W_out,  // 48
    const float* __restrict__ b_out,  // 1
    float* __restrict__ out)          // 64
{
    __shared__ __align__(16) float sh_h[HID];
    __shared__ float sh_g[NG];
    __shared__ float sh_p[HID];
    __shared__ float sh_v[2];

    const int j = threadIdx.x;

    // per-thread gate row weights in registers
    float w[HID];
#pragma unroll
    for (int i = 0; i < HID / 4; ++i) {
        float4 t4 = *(const float4*)(W_hh + j * HID + 4 * i);
        w[4 * i + 0] = t4.x;
        w[4 * i + 1] = t4.y;
        w[4 * i + 2] = t4.z;
        w[4 * i + 3] = t4.w;
    }
    const float wi0 = W_ih[2 * j];
    const float wi1 = W_ih[2 * j + 1];
    const float bsum = b_ih[j] + b_hh[j];
    const float wo = (j < HID) ? W_out[j] : 0.0f;
    const float bo = b_out[0];

    float c = 0.0f;
    if (j < HID) sh_h[j] = 0.0f;
    __syncthreads();

    float x0 = x[0];
    float x1 = x[1];

    // ---------------- encoder: 131072 sequential steps ----------------
    for (int t = 0; t < SEQL; ++t) {
        // prefetch next step's x (uniform broadcast load, hidden under compute)
        float nx0 = 0.0f, nx1 = 0.0f;
        if (t + 1 < SEQL) {
            nx0 = x[2 * t + 2];
            nx1 = x[2 * t + 3];
        }

        // gate j = x·W_ih[j] + b_ih[j] + b_hh[j] + W_hh[j]·h
        float a0 = fmaf(x1, wi1, fmaf(x0, wi0, bsum));
        float a1 = 0.0f, a2 = 0.0f, a3 = 0.0f;
#pragma unroll
        for (int i = 0; i < HID / 4; ++i) {
            float4 hv = *(const float4*)(sh_h + 4 * i);  // broadcast LDS read
            a0 = fmaf(w[4 * i + 0], hv.x, a0);
            a1 = fmaf(w[4 * i + 1], hv.y, a1);
            a2 = fmaf(w[4 * i + 2], hv.z, a2);
            a3 = fmaf(w[4 * i + 3], hv.w, a3);
        }
        sh_g[j] = (a0 + a1) + (a2 + a3);
        __syncthreads();

        if (j < HID) {
            float gi = sh_g[j];
            float gf = sh_g[j + HID];
            float gg = sh_g[j + 2 * HID];
            float go = sh_g[j + 3 * HID];
            float cn = fmaf(sigm(gf), c, sigm(gi) * tanh_fast(gg));
            c = cn;
            sh_h[j] = sigm(go) * tanh_fast(cn);
        }
        __syncthreads();

        x0 = nx0;
        x1 = nx1;
    }

    // ---------------- out0 ----------------
    if (j < HID) sh_p[j] = wo * sh_h[j];
    __syncthreads();
    if (j == 0) {
        float s = bo;
        for (int i = 0; i < HID; ++i) s += sh_p[i];
        out[0] = s;
        sh_v[0] = x[2 * SEQL - 1];  // last raw input scalar
        sh_v[1] = s;                // out0
    }
    __syncthreads();

    // ---------------- autoregressive decoder: 63 steps ----------------
    for (int d = 1; d < PRED; ++d) {
        float xv0 = sh_v[0];
        float xv1 = sh_v[1];

        float a0 = fmaf(xv1, wi1, fmaf(xv0, wi0, bsum));
        float a1 = 0.0f, a2 = 0.0f, a3 = 0.0f;
#pragma unroll
        for (int i = 0; i < HID / 4; ++i) {
            float4 hv = *(const float4*)(sh_h + 4 * i);
            a0 = fmaf(w[4 * i + 0], hv.x, a0);
            a1 = fmaf(w[4 * i + 1], hv.y, a1);
            a2 = fmaf(w[4 * i + 2], hv.z, a2);
            a3 = fmaf(w[4 * i + 3], hv.w, a3);
        }
        sh_g[j] = (a0 + a1) + (a2 + a3);
        __syncthreads();

        if (j < HID) {
            float gi = sh_g[j];
            float gf = sh_g[j + HID];
            float gg = sh_g[j + 2 * HID];
            float go = sh_g[j + 3 * HID];
            float cn = fmaf(sigm(gf), c, sigm(gi) * tanh_fast(gg));
            c = cn;
            float hn = sigm(go) * tanh_fast(cn);
            sh_h[j] = hn;
            sh_p[j] = wo * hn;
        }
        __syncthreads();

        if (j == 0) {
            float s = bo;
            for (int i = 0; i < HID; ++i) s += sh_p[i];
            out[d] = s;
            sh_v[0] = sh_v[1];
            sh_v[1] = s;
        }
        __syncthreads();
    }
}

extern "C" void kernel_launch(void* const* d_in, const int* in_sizes, int n_in,
                              void* d_out, int out_size, void* d_ws, size_t ws_size,
                              hipStream_t stream) {
    const float* x     = (const float*)d_in[0];
    const float* W_ih  = (const float*)d_in[1];
    const float* W_hh  = (const float*)d_in[2];
    const float* b_ih  = (const float*)d_in[3];
    const float* b_hh  = (const float*)d_in[4];
    const float* W_out = (const float*)d_in[5];
    const float* b_out = (const float*)d_in[6];
    float* out = (float*)d_out;

    hipLaunchKernelGGL(lstm_all, dim3(1), dim3(NG), 0, stream,
                       x, W_ih, W_hh, b_ih, b_hh, W_out, b_out, out);
}

// Round 2
// 63154.047 us; speedup vs baseline: 1.1056x; 1.1056x over previous
//
#include <hip/hip_runtime.h>

#define SEQL 131072
#define HID 48
#define PRED 64

typedef float f32x2 __attribute__((ext_vector_type(2)));

__device__ __forceinline__ float sigm(float v) {
    return 1.0f / (1.0f + __expf(-v));
}
__device__ __forceinline__ float tanh_fast(float v) {
    return 1.0f - 2.0f / (__expf(2.0f * v) + 1.0f);
}

// packed fp32 FMA: acc.lo += a.lo*b.lo, acc.hi += a.hi*b.hi  (gfx90a+ VOP3P)
__device__ __forceinline__ void pkfma(f32x2& acc, f32x2 a, f32x2 b) {
    asm("v_pk_fma_f32 %0, %1, %2, %0" : "+v"(acc) : "v"(a), "v"(b));
}

__device__ __forceinline__ float wave_sum(float v) {
#pragma unroll
    for (int off = 32; off > 0; off >>= 1) v += __shfl_xor(v, off, 64);
    return v;
}

// One LSTM cell step. Lane k (<48) owns hidden unit k and gate rows
// k, k+48, k+96, k+144. h is broadcast through LDS (single wave -> DS ops
// are in-order, no barrier needed). Returns new h_k (garbage 0 for k>=48).
__device__ __forceinline__ float lstm_step(
    float x0, float x1, int k,
    const f32x2* w0, const f32x2* w1, const f32x2* w2, const f32x2* w3,
    float4 wx01, float4 wx23, float4 bs, float& c, float* sh_h)
{
    f32x2 a0 = {0.f, 0.f}, a1 = {0.f, 0.f}, a2 = {0.f, 0.f}, a3 = {0.f, 0.f};
#pragma unroll
    for (int i = 0; i < HID / 2; ++i) {
        f32x2 hp = *(const f32x2*)(sh_h + 2 * i);  // broadcast read, no conflict
        pkfma(a0, w0[i], hp);
        pkfma(a1, w1[i], hp);
        pkfma(a2, w2[i], hp);
        pkfma(a3, w3[i], hp);
    }
    float gi = (a0.x + a0.y) + fmaf(x0, wx01.x, fmaf(x1, wx01.y, bs.x));
    float gf = (a1.x + a1.y) + fmaf(x0, wx01.z, fmaf(x1, wx01.w, bs.y));
    float gg = (a2.x + a2.y) + fmaf(x0, wx23.x, fmaf(x1, wx23.y, bs.z));
    float go = (a3.x + a3.y) + fmaf(x0, wx23.z, fmaf(x1, wx23.w, bs.w));
    float c2 = fmaf(sigm(gf), c, sigm(gi) * tanh_fast(gg));
    c = c2;
    float h = sigm(go) * tanh_fast(c2);
    sh_h[k] = h;  // lanes >=48 write to the padding slots (h==0 there anyway)
    return h;
}

__global__ __launch_bounds__(64, 1) void lstm_all(
    const float* __restrict__ x,      // 2*SEQL
    const float* __restrict__ W_ih,   // 192*2
    const float* __restrict__ W_hh,   // 192*48
    const float* __restrict__ b_ih,   // 192
    const float* __restrict__ b_hh,   // 192
    const float* __restrict__ W_out,  // 48
    const float* __restrict__ b_out,  // 1
    float* __restrict__ out)          // 64
{
    __shared__ __align__(16) float sh_h[64];  // 48 live + 16 padding slots

    const int k = threadIdx.x;
    const bool live = (k < HID);
    const int r0 = live ? k : 0;
    const int r1 = r0 + HID, r2 = r0 + 2 * HID, r3 = r0 + 3 * HID;

    // ---- weights into VGPRs (4 rows x 24 float2 = 192 VGPRs) ----
    f32x2 w0[HID / 2], w1[HID / 2], w2[HID / 2], w3[HID / 2];
#pragma unroll
    for (int i = 0; i < HID / 2; ++i) {
        if (live) {
            w0[i] = *(const f32x2*)(W_hh + r0 * HID + 2 * i);
            w1[i] = *(const f32x2*)(W_hh + r1 * HID + 2 * i);
            w2[i] = *(const f32x2*)(W_hh + r2 * HID + 2 * i);
            w3[i] = *(const f32x2*)(W_hh + r3 * HID + 2 * i);
        } else {
            w0[i] = (f32x2){0.f, 0.f}; w1[i] = (f32x2){0.f, 0.f};
            w2[i] = (f32x2){0.f, 0.f}; w3[i] = (f32x2){0.f, 0.f};
        }
    }
    float4 wx01, wx23, bs;
    if (live) {
        wx01 = make_float4(W_ih[2 * r0], W_ih[2 * r0 + 1], W_ih[2 * r1], W_ih[2 * r1 + 1]);
        wx23 = make_float4(W_ih[2 * r2], W_ih[2 * r2 + 1], W_ih[2 * r3], W_ih[2 * r3 + 1]);
        bs = make_float4(b_ih[r0] + b_hh[r0], b_ih[r1] + b_hh[r1],
                         b_ih[r2] + b_hh[r2], b_ih[r3] + b_hh[r3]);
    } else {
        wx01 = make_float4(0.f, 0.f, 0.f, 0.f);
        wx23 = wx01; bs = wx01;
    }
    const float wo = live ? W_out[r0] : 0.0f;
    const float bo = b_out[0];

    float c = 0.0f;
    sh_h[k] = 0.0f;  // in-order DS within the wave: ordered before first reads

    // ---- encoder: 131072 sequential steps, x prefetched 4 deep ----
    const float2* xp = (const float2*)x;
    float2 xq0 = xp[0], xq1 = xp[1], xq2 = xp[2], xq3 = xp[3];
    float h = 0.0f;
    for (int t = 0; t < SEQL; ++t) {
        int tn = t + 4;
        if (tn > SEQL - 1) tn = SEQL - 1;
        float2 xn = xp[tn];  // issued now, consumed 4 steps later
        h = lstm_step(xq0.x, xq0.y, k, w0, w1, w2, w3, wx01, wx23, bs, c, sh_h);
        xq0 = xq1; xq1 = xq2; xq2 = xq3; xq3 = xn;
    }

    // ---- out0 ----
    float y = wave_sum(wo * h) + bo;
    if (k == 0) out[0] = y;

    // ---- autoregressive decoder ----
    float v0 = xp[SEQL - 1].y;  // last raw input scalar
    float v1 = y;
    for (int d = 1; d < PRED; ++d) {
        h = lstm_step(v0, v1, k, w0, w1, w2, w3, wx01, wx23, bs, c, sh_h);
        float yd = wave_sum(wo * h) + bo;
        if (k == 0) out[d] = yd;
        v0 = v1; v1 = yd;
    }
}

extern "C" void kernel_launch(void* const* d_in, const int* in_sizes, int n_in,
                              void* d_out, int out_size, void* d_ws, size_t ws_size,
                              hipStream_t stream) {
    const float* x     = (const float*)d_in[0];
    const float* W_ih  = (const float*)d_in[1];
    const float* W_hh  = (const float*)d_in[2];
    const float* b_ih  = (const float*)d_in[3];
    const float* b_hh  = (const float*)d_in[4];
    const float* W_out = (const float*)d_in[5];
    const float* b_out = (const float*)d_in[6];
    float* out = (float*)d_out;

    hipLaunchKernelGGL(lstm_all, dim3(1), dim3(64), 0, stream,
                       x, W_ih, W_hh, b_ih, b_hh, W_out, b_out, out);
}